// Round 1
// baseline (107.576 us; speedup 1.0000x reference)
//
#include <hip/hip_runtime.h>
#include <math.h>

// Rational-quadratic spline, K=8 bins, tail B=3.
// Per element: softmax widths/heights -> knots, softplus derivs,
// bin search by count, RQ transform + log|det| (summed).

#define NBINS 8
#define TAILB 3.0f
#define MINSZ 0.001f
#define EPSL 1e-6f

__launch_bounds__(256, 4)
__global__ void rqs_kernel(const float* __restrict__ x_in,
                           const float* __restrict__ params,
                           float* __restrict__ out,
                           float* __restrict__ partial,
                           int n)
{
    __shared__ __align__(16) float lds[256 * 25];
    __shared__ double wsum[4];

    const int tid = threadIdx.x;
    const int base_row = blockIdx.x * 256;

    // ---- stage 256 rows x 25 floats into LDS, coalesced float4 ----
    // block chunk = 6400 floats = 1600 float4, base is 16B aligned.
    const float4* src = reinterpret_cast<const float4*>(params) + (size_t)blockIdx.x * 1600;
    float4* dst = reinterpret_cast<float4*>(lds);
    #pragma unroll
    for (int v = 0; v < 7; ++v) {
        int q = tid + v * 256;
        if (q < 1600) dst[q] = src[q];
    }
    __syncthreads();

    const int i = base_row + tid;
    const float x = x_in[i];

    // row into registers (static indexing everywhere after unroll)
    float p[25];
    #pragma unroll
    for (int j = 0; j < 25; ++j) p[j] = lds[tid * 25 + j];

    const float xi = fminf(fmaxf(x, -TAILB), TAILB);

    // ---- widths: softmax -> scaled -> cumsum knots ----
    float mw = p[0];
    #pragma unroll
    for (int j = 1; j < 8; ++j) mw = fmaxf(mw, p[j]);
    float ew[8]; float sw = 0.f;
    #pragma unroll
    for (int j = 0; j < 8; ++j) { ew[j] = __expf(p[j] - mw); sw += ew[j]; }
    // w = softmax*6 * (6 - 8*0.001) + 0.001
    const float facw = (2.0f * TAILB) * (2.0f * TAILB - (float)NBINS * MINSZ) / sw;
    float Kn[9];
    Kn[0] = -TAILB;
    {
        float c = 0.f;
        #pragma unroll
        for (int j = 0; j < 7; ++j) { c += ew[j] * facw + MINSZ; Kn[j + 1] = c; }
    }
    Kn[8] = TAILB;

    // ---- bin index: count of (xi >= bin_loc_j) - 1 ----
    // bin_loc[0]=-3 always <= xi ; bin_loc[8]=3+eps never <= xi
    int idx = 0;
    #pragma unroll
    for (int j = 1; j < 8; ++j) idx += (xi >= Kn[j]) ? 1 : 0;

    // ---- heights ----
    float mh = p[8];
    #pragma unroll
    for (int j = 1; j < 8; ++j) mh = fmaxf(mh, p[8 + j]);
    float eh[8]; float sh = 0.f;
    #pragma unroll
    for (int j = 0; j < 8; ++j) { eh[j] = __expf(p[8 + j] - mh); sh += eh[j]; }
    const float fach = (2.0f * TAILB) * (2.0f * TAILB - (float)NBINS * MINSZ) / sh;
    float Hn[9];
    Hn[0] = -TAILB;
    {
        float c = 0.f;
        #pragma unroll
        for (int j = 0; j < 7; ++j) { c += eh[j] * fach + MINSZ; Hn[j + 1] = c; }
    }
    Hn[8] = TAILB;

    // ---- derivatives: softplus(ud)+0.001, 9 of them ----
    float dv[9];
    #pragma unroll
    for (int j = 0; j < 9; ++j) {
        float u = p[16 + j];
        float t = __expf(-fabsf(u));
        dv[j] = fmaxf(u, 0.f) + __logf(1.0f + t) + MINSZ;
    }

    // ---- gathers via unrolled selects (keep arrays in registers) ----
    float cw_k = Kn[0], cw_k1 = Kn[1];
    float ch_k = Hn[0], ch_k1 = Hn[1];
    float d_k = dv[0], d_k1 = dv[1];
    #pragma unroll
    for (int j = 1; j < 8; ++j) {
        bool sel = (idx == j);
        cw_k  = sel ? Kn[j]     : cw_k;
        cw_k1 = sel ? Kn[j + 1] : cw_k1;
        ch_k  = sel ? Hn[j]     : ch_k;
        ch_k1 = sel ? Hn[j + 1] : ch_k1;
        d_k   = sel ? dv[j]     : d_k;
        d_k1  = sel ? dv[j + 1] : d_k1;
    }

    // ---- rational-quadratic transform ----
    const float bw  = cw_k1 - cw_k;
    const float bh  = ch_k1 - ch_k;
    const float th  = (xi - cw_k) / bw;
    const float omt = 1.0f - th;
    const float th2 = th * th;
    const float t1m = th * omt;
    const float num = bh * (d_k * th2 + d_k1 * t1m);
    const float den = d_k * th2 + 2.0f * d_k1 * t1m + omt * omt;
    const float out_in = ch_k + num / den;
    // log(dk1*dk*bh*den^2 / (bw*den^2)) == log(dk1*dk*bh/bw)
    const float ld_in = __logf((d_k1 * d_k * bh) / bw);

    const bool inside = (x >= -TAILB) && (x <= TAILB);
    const float outv = inside ? out_in : x;
    const float ldv  = inside ? ld_in : __logf(dv[0]);

    out[i] = outv;

    // ---- block reduction of ldv (double, deterministic order) ----
    double acc = (double)ldv;
    #pragma unroll
    for (int off = 32; off > 0; off >>= 1)
        acc += __shfl_down(acc, off);
    const int wave = tid >> 6, lane = tid & 63;
    if (lane == 0) wsum[wave] = acc;
    __syncthreads();
    if (tid == 0)
        partial[blockIdx.x] = (float)(wsum[0] + wsum[1] + wsum[2] + wsum[3]);
}

__global__ void rqs_reduce(const float* __restrict__ partial, int nb,
                           float* __restrict__ out_sum)
{
    const int tid = threadIdx.x;
    double acc = 0.0;
    for (int i = tid; i < nb; i += 256) acc += (double)partial[i];
    #pragma unroll
    for (int off = 32; off > 0; off >>= 1)
        acc += __shfl_down(acc, off);
    __shared__ double wsum[4];
    const int wave = tid >> 6, lane = tid & 63;
    if (lane == 0) wsum[wave] = acc;
    __syncthreads();
    if (tid == 0) *out_sum = (float)(wsum[0] + wsum[1] + wsum[2] + wsum[3]);
}

extern "C" void kernel_launch(void* const* d_in, const int* in_sizes, int n_in,
                              void* d_out, int out_size, void* d_ws, size_t ws_size,
                              hipStream_t stream) {
    const float* x      = (const float*)d_in[0];
    const float* params = (const float*)d_in[1];
    float* out = (float*)d_out;
    const int n = in_sizes[0];          // 4194304, divisible by 256
    const int nb = n / 256;             // 16384 blocks
    float* partial = (float*)d_ws;      // nb*4 = 64 KB scratch

    hipLaunchKernelGGL(rqs_kernel, dim3(nb), dim3(256), 0, stream,
                       x, params, out, partial, n);
    hipLaunchKernelGGL(rqs_reduce, dim3(1), dim3(256), 0, stream,
                       partial, nb, out + n);
}

// Round 2
// 88.015 us; speedup vs baseline: 1.2222x; 1.2222x over previous
//
#include <hip/hip_runtime.h>
#include <math.h>

// Rational-quadratic spline, K=8 bins, tail B=3.
// R2: 3-phase LDS reads + on-the-fly knot select (only 3 softplus),
//     global_load_lds staging, launch_bounds(256,6) for 6 blocks/CU.

#define TAILB 3.0f
#define MINSZ 0.001f

typedef unsigned int u32;

__device__ __forceinline__ void gload_lds16(const void* g, void* l) {
    __builtin_amdgcn_global_load_lds(
        (const __attribute__((address_space(1))) u32*)g,
        (__attribute__((address_space(3))) u32*)l,
        16, 0, 0);
}

__device__ __forceinline__ float softplus_d(float u) {
    // softplus(u) + MIN_D
    return fmaxf(u, 0.0f) + __logf(1.0f + __expf(-fabsf(u))) + MINSZ;
}

__launch_bounds__(256, 6)
__global__ void rqs_kernel(const float* __restrict__ x_in,
                           const float* __restrict__ params,
                           float* __restrict__ out,
                           float* __restrict__ partial)
{
    __shared__ __align__(16) float lds[256 * 25];
    __shared__ double wsum[4];

    const int tid = threadIdx.x;
    const int i = blockIdx.x * 256 + tid;

    // ---- stage 256 rows x 25 floats (25600 B) directly global->LDS ----
    // 1600 float4 chunks; linear dest = base + lane*16 (global_load_lds's
    // required layout). Iter 6 is exactly wave 0 (q = 1536..1599).
    const float4* src = (const float4*)params + (size_t)blockIdx.x * 1600;
    float4* dst = (float4*)lds;
    #pragma unroll
    for (int v = 0; v < 6; ++v) {
        const int q = tid + v * 256;
        gload_lds16(src + q, dst + q);
    }
    if (tid < 64) {
        const int q = tid + 1536;
        gload_lds16(src + q, dst + q);
    }

    // overlap x-load with the staging
    const float x = x_in[i];
    const float xi = fminf(fmaxf(x, -TAILB), TAILB);

    __syncthreads();

    const float* row = &lds[tid * 25];
    const float fac_num = (2.0f * TAILB) * (2.0f * TAILB - 8.0f * MINSZ); // 35.952

    // ---- phase W: widths softmax -> cumsum knots; bin index by count ----
    float ew[8];
    float facw;
    {
        float u[8];
        #pragma unroll
        for (int j = 0; j < 8; ++j) u[j] = row[j];
        float m = u[0];
        #pragma unroll
        for (int j = 1; j < 8; ++j) m = fmaxf(m, u[j]);
        float s = 0.0f;
        #pragma unroll
        for (int j = 0; j < 8; ++j) { ew[j] = __expf(u[j] - m); s += ew[j]; }
        facw = fac_num / s;
    }
    // count pass: idx = #{ j in 1..7 : xi >= Kn[j] }
    float c = 0.0f;
    int idx = 0;
    #pragma unroll
    for (int j = 0; j < 7; ++j) {
        c += ew[j] * facw + MINSZ;
        idx += (xi >= c) ? 1 : 0;
    }
    // select pass: cw_k = Kn[idx], cw_k1 = Kn[idx+1]  (Kn[0]=-B, Kn[8]=B)
    float cw_k = -TAILB, cw_k1 = TAILB;
    c = 0.0f;
    #pragma unroll
    for (int j = 1; j <= 7; ++j) {
        c += ew[j - 1] * facw + MINSZ;
        cw_k  = (idx == j)     ? c : cw_k;
        cw_k1 = (idx + 1 == j) ? c : cw_k1;
    }

    // ---- phase H: heights softmax -> select knots with known idx ----
    float ch_k = -TAILB, ch_k1 = TAILB;
    {
        float eh[8];
        float u[8];
        #pragma unroll
        for (int j = 0; j < 8; ++j) u[j] = row[8 + j];
        float m = u[0];
        #pragma unroll
        for (int j = 1; j < 8; ++j) m = fmaxf(m, u[j]);
        float s = 0.0f;
        #pragma unroll
        for (int j = 0; j < 8; ++j) { eh[j] = __expf(u[j] - m); s += eh[j]; }
        const float fach = fac_num / s;
        c = 0.0f;
        #pragma unroll
        for (int j = 1; j <= 7; ++j) {
            c += eh[j - 1] * fach + MINSZ;
            ch_k  = (idx == j)     ? c : ch_k;
            ch_k1 = (idx + 1 == j) ? c : ch_k1;
        }
    }

    // ---- phase D: only the 3 derivatives we need (dynamic LDS gather) ----
    const float d0  = softplus_d(row[16]);
    const float d_k  = (idx == 0) ? d0 : softplus_d(row[16 + idx]);
    const float d_k1 = softplus_d(row[17 + idx]);

    // ---- rational-quadratic transform ----
    const float bw  = cw_k1 - cw_k;
    const float bh  = ch_k1 - ch_k;
    const float th  = (xi - cw_k) / bw;
    const float omt = 1.0f - th;
    const float th2 = th * th;
    const float t1m = th * omt;
    const float num = bh * (d_k * th2 + d_k1 * t1m);
    const float den = d_k * th2 + 2.0f * d_k1 * t1m + omt * omt;
    const float out_in = ch_k + num / den;
    // log(dk1*dk*bh*den^2 / (bw*den^2)) == log(dk1*dk*bh/bw)
    const float ld_in = __logf((d_k1 * d_k * bh) / bw);

    const bool inside = (x >= -TAILB) && (x <= TAILB);
    out[i] = inside ? out_in : x;
    const float ldv = inside ? ld_in : __logf(d0);

    // ---- block reduction of ldv (double, deterministic order) ----
    double acc = (double)ldv;
    #pragma unroll
    for (int off = 32; off > 0; off >>= 1)
        acc += __shfl_down(acc, off);
    const int wave = tid >> 6, lane = tid & 63;
    if (lane == 0) wsum[wave] = acc;
    __syncthreads();
    if (tid == 0)
        partial[blockIdx.x] = (float)(wsum[0] + wsum[1] + wsum[2] + wsum[3]);
}

__global__ void rqs_reduce(const float* __restrict__ partial, int nb,
                           float* __restrict__ out_sum)
{
    const int tid = threadIdx.x;              // 1024 threads
    const int nb4 = nb >> 2;                  // nb divisible by 4
    const float4* p4 = (const float4*)partial;
    double acc = 0.0;
    for (int q = tid; q < nb4; q += 1024) {
        float4 v = p4[q];
        acc += (double)v.x + (double)v.y + (double)v.z + (double)v.w;
    }
    #pragma unroll
    for (int off = 32; off > 0; off >>= 1)
        acc += __shfl_down(acc, off);
    __shared__ double wsum[16];
    const int wave = tid >> 6, lane = tid & 63;
    if (lane == 0) wsum[wave] = acc;
    __syncthreads();
    if (tid == 0) {
        double t = 0.0;
        #pragma unroll
        for (int w = 0; w < 16; ++w) t += wsum[w];
        *out_sum = (float)t;
    }
}

extern "C" void kernel_launch(void* const* d_in, const int* in_sizes, int n_in,
                              void* d_out, int out_size, void* d_ws, size_t ws_size,
                              hipStream_t stream) {
    const float* x      = (const float*)d_in[0];
    const float* params = (const float*)d_in[1];
    float* out = (float*)d_out;
    const int n = in_sizes[0];          // 4194304, divisible by 256
    const int nb = n / 256;             // 16384 blocks
    float* partial = (float*)d_ws;      // nb*4 = 64 KB scratch

    hipLaunchKernelGGL(rqs_kernel, dim3(nb), dim3(256), 0, stream,
                       x, params, out, partial);
    hipLaunchKernelGGL(rqs_reduce, dim3(1), dim3(1024), 0, stream,
                       partial, nb, out + n);
}